// Round 3
// baseline (183.050 us; speedup 1.0000x reference)
//
#include <hip/hip_runtime.h>
#include <math.h>

// Problem constants (fixed by the reference)
#define BB   64
#define NN   131072
#define KTAPS 5
#define TILE 1024          // elements per block (256 threads x 4)
#define NTHREADS 256

// 2*pi / sampling_freq
#define ANG_PER_HZ 2.0453077171808549e-7f   // float(2*pi/30720000.0)
// 10*log10(1.5)
#define EBNO_OFF   1.7609125905568124f
// log2(10)/20
#define L2TEN_OVER20 0.16609640474436813f

// Rotate two consecutive elements starting at idx by exp(i*ang*n).
// Returns {r0, i0, r1, i1}. Zero-pads outside [0, NN).
__device__ __forceinline__ float4 rot_edge2(const float* __restrict__ xr,
                                            const float* __restrict__ xi,
                                            size_t rowoff, int idx, float ang,
                                            float sA, float cA) {
    float4 r = make_float4(0.0f, 0.0f, 0.0f, 0.0f);
    if (idx >= 0 && idx + 1 < NN) {
        float2 a = *reinterpret_cast<const float2*>(xr + rowoff + (size_t)idx);
        float2 b = *reinterpret_cast<const float2*>(xi + rowoff + (size_t)idx);
        float ss, cc;
        sincosf(ang * (float)idx, &ss, &cc);
        r.x = a.x * cc - b.x * ss;
        r.y = a.x * ss + b.x * cc;
        float cn = cc * cA - ss * sA;
        float sn = ss * cA + cc * sA;
        r.z = a.y * cn - b.y * sn;
        r.w = a.y * sn + b.y * cn;
    }
    return r;
}

__global__ __launch_bounds__(NTHREADS) void wc_kernel(
    const float* __restrict__ x_real,  const float* __restrict__ x_imag,
    const float* __restrict__ ebno_db, const float* __restrict__ cfo_u,
    const float* __restrict__ taps_real, const float* __restrict__ taps_imag,
    const float* __restrict__ noise_real, const float* __restrict__ noise_imag,
    float* __restrict__ out)
{
    const int b    = blockIdx.y;
    const int tid  = threadIdx.x;
    const int base = blockIdx.x * TILE + tid * 4;   // first of my 4 elements
    const int lane = tid & 63;
    const size_t rowoff = (size_t)b * NN;

    // ---- per-batch scalars ----
    const float cfo     = cfo_u[b];
    const float delta_f = (cfo * 2.0f - 1.0f) * 0.05f * 15000.0f;
    const float ang     = delta_f * ANG_PER_HZ;        // radians per sample
    const float snr     = ebno_db[b] + EBNO_OFF;
    const float scale   = 0.5f * exp2f(-snr * L2TEN_OVER20);

    float tr[KTAPS], ti[KTAPS];
#pragma unroll
    for (int k = 0; k < KTAPS; ++k) {
        tr[k] = taps_real[b * KTAPS + k];
        ti[k] = taps_imag[b * KTAPS + k];
    }

    // ---- vector loads ----
    const float4 xr4 = *reinterpret_cast<const float4*>(x_real + rowoff + base);
    const float4 xi4 = *reinterpret_cast<const float4*>(x_imag + rowoff + base);
    const float xr_[4] = {xr4.x, xr4.y, xr4.z, xr4.w};
    const float xi_[4] = {xi4.x, xi4.y, xi4.z, xi4.w};

    // ---- CFO rotation: sincos once, then angle-addition recurrence ----
    float sA, cA, s, c;
    sincosf(ang, &sA, &cA);
    sincosf(ang * (float)base, &s, &c);

    // window wr/wi[0..7] = rotated elements base-2 .. base+5
    float wr[8], wi[8];
#pragma unroll
    for (int j = 0; j < 4; ++j) {
        wr[2 + j] = xr_[j] * c - xi_[j] * s;
        wi[2 + j] = xr_[j] * s + xi_[j] * c;
        float cn = c * cA - s * sA;
        float sn = s * cA + c * sA;
        c = cn; s = sn;
    }

    // ---- halo via wave shuffles (width 64) ----
    wr[0] = __shfl_up(wr[4], 1, 64);   // prev thread's base+2 -> my base-2
    wr[1] = __shfl_up(wr[5], 1, 64);
    wi[0] = __shfl_up(wi[4], 1, 64);
    wi[1] = __shfl_up(wi[5], 1, 64);
    wr[6] = __shfl_down(wr[2], 1, 64); // next thread's base -> my base+4
    wr[7] = __shfl_down(wr[3], 1, 64);
    wi[6] = __shfl_down(wi[2], 1, 64);
    wi[7] = __shfl_down(wi[3], 1, 64);

    // wave-edge lanes: fetch + rotate their halo from global (L2-hit, rare)
    if (lane == 0) {
        float4 e = rot_edge2(x_real, x_imag, rowoff, base - 2, ang, sA, cA);
        wr[0] = e.x; wi[0] = e.y;
        wr[1] = e.z; wi[1] = e.w;
    }
    if (lane == 63) {
        float4 e = rot_edge2(x_real, x_imag, rowoff, base + 4, ang, sA, cA);
        wr[6] = e.x; wi[6] = e.y;
        wr[7] = e.z; wi[7] = e.w;
    }

    // ---- 5-tap complex conv (cross-correlation) + AWGN ----
    const float4 nr4 = *reinterpret_cast<const float4*>(noise_real + rowoff + base);
    const float4 ni4 = *reinterpret_cast<const float4*>(noise_imag + rowoff + base);
    const float nr_[4] = {nr4.x, nr4.y, nr4.z, nr4.w};
    const float ni_[4] = {ni4.x, ni4.y, ni4.z, ni4.w};

    float oyr[4], oyi[4];
#pragma unroll
    for (int j = 0; j < 4; ++j) {
        float ar = 0.0f, ai = 0.0f;
#pragma unroll
        for (int k = 0; k < KTAPS; ++k) {
            ar = fmaf(tr[k], wr[j + k], ar);
            ar = fmaf(-ti[k], wi[j + k], ar);
            ai = fmaf(ti[k], wr[j + k], ai);
            ai = fmaf(tr[k], wi[j + k], ai);
        }
        oyr[j] = fmaf(nr_[j], scale, ar);
        oyi[j] = fmaf(ni_[j], scale, ai);
    }

    float4 yr4 = make_float4(oyr[0], oyr[1], oyr[2], oyr[3]);
    float4 yi4 = make_float4(oyi[0], oyi[1], oyi[2], oyi[3]);
    *reinterpret_cast<float4*>(out + rowoff + base) = yr4;
    *reinterpret_cast<float4*>(out + (size_t)BB * NN + rowoff + base) = yi4;
}

extern "C" void kernel_launch(void* const* d_in, const int* in_sizes, int n_in,
                              void* d_out, int out_size, void* d_ws, size_t ws_size,
                              hipStream_t stream) {
    const float* x_real     = (const float*)d_in[0];
    const float* x_imag     = (const float*)d_in[1];
    const float* ebno_db    = (const float*)d_in[2];
    const float* cfo_u      = (const float*)d_in[3];
    const float* taps_real  = (const float*)d_in[4];
    const float* taps_imag  = (const float*)d_in[5];
    const float* noise_real = (const float*)d_in[6];
    const float* noise_imag = (const float*)d_in[7];

    dim3 grid(NN / TILE, BB);
    wc_kernel<<<grid, NTHREADS, 0, stream>>>(
        x_real, x_imag, ebno_db, cfo_u, taps_real, taps_imag,
        noise_real, noise_imag, (float*)d_out);
}

// Round 4
// 180.790 us; speedup vs baseline: 1.0125x; 1.0125x over previous
//
#include <hip/hip_runtime.h>
#include <math.h>

// Problem constants (fixed by the reference)
#define BB   64
#define NN   131072
#define KTAPS 5
#define TILE 1024          // elements per block (256 threads x 4)
#define NTHREADS 256

// 2*pi / sampling_freq
#define ANG_PER_HZ 2.0453077171808549e-7f   // float(2*pi/30720000.0)
// 10*log10(1.5)
#define EBNO_OFF   1.7609125905568124f
// log2(10)/20
#define L2TEN_OVER20 0.16609640474436813f

typedef float f32x4 __attribute__((ext_vector_type(4)));

__global__ __launch_bounds__(NTHREADS) void wc_kernel(
    const float* __restrict__ x_real,  const float* __restrict__ x_imag,
    const float* __restrict__ ebno_db, const float* __restrict__ cfo_u,
    const float* __restrict__ taps_real, const float* __restrict__ taps_imag,
    const float* __restrict__ noise_real, const float* __restrict__ noise_imag,
    float* __restrict__ out)
{
    const int b    = blockIdx.y;
    const int base = blockIdx.x * TILE + threadIdx.x * 4;  // first of my 4 elems
    const size_t rowoff = (size_t)b * NN;

    const float* __restrict__ xr = x_real + rowoff;
    const float* __restrict__ xi = x_imag + rowoff;

    // Clamped overlapping window loads: cover idx base-4 .. base+7.
    // Overlap is served by L1/L2; HBM traffic unchanged.
    const int aL = (base == 0)       ? 0        : base - 4;
    const int aR = (base == NN - 4)  ? NN - 4   : base + 4;

    // ---- issue ALL global loads up front (independent; latency overlaps trig) ----
    const float4 xrL = *reinterpret_cast<const float4*>(xr + aL);
    const float4 xr0 = *reinterpret_cast<const float4*>(xr + base);
    const float4 xrR = *reinterpret_cast<const float4*>(xr + aR);
    const float4 xiL = *reinterpret_cast<const float4*>(xi + aL);
    const float4 xi0 = *reinterpret_cast<const float4*>(xi + base);
    const float4 xiR = *reinterpret_cast<const float4*>(xi + aR);
    const float4 nr4 = *reinterpret_cast<const float4*>(noise_real + rowoff + base);
    const float4 ni4 = *reinterpret_cast<const float4*>(noise_imag + rowoff + base);

    // ---- per-batch scalars (uniform -> s_load) ----
    const float cfo     = cfo_u[b];
    const float delta_f = (cfo * 2.0f - 1.0f) * 0.05f * 15000.0f;
    const float ang     = delta_f * ANG_PER_HZ;        // radians per sample
    const float snr     = ebno_db[b] + EBNO_OFF;
    const float scale   = 0.5f * exp2f(-snr * L2TEN_OVER20);

    float tr[KTAPS], ti[KTAPS];
#pragma unroll
    for (int k = 0; k < KTAPS; ++k) {
        tr[k] = taps_real[b * KTAPS + k];
        ti[k] = taps_imag[b * KTAPS + k];
    }

    // ---- trig (independent of loads; runs under memory latency) ----
    float sA, cA, s, c;
    sincosf(ang, &sA, &cA);
    sincosf(ang * (float)(base - 2), &s, &c);

    // ---- assemble window idx = base-2 .. base+5, branchless edge masks ----
    const bool lok = (base != 0);
    const bool rok = (base != NN - 4);

    float ur[8], ui[8];
    ur[0] = lok ? xrL.z : 0.0f;  ui[0] = lok ? xiL.z : 0.0f;
    ur[1] = lok ? xrL.w : 0.0f;  ui[1] = lok ? xiL.w : 0.0f;
    ur[2] = xr0.x;  ui[2] = xi0.x;
    ur[3] = xr0.y;  ui[3] = xi0.y;
    ur[4] = xr0.z;  ui[4] = xi0.z;
    ur[5] = xr0.w;  ui[5] = xi0.w;
    ur[6] = rok ? xrR.x : 0.0f;  ui[6] = rok ? xiR.x : 0.0f;
    ur[7] = rok ? xrR.y : 0.0f;  ui[7] = rok ? xiR.y : 0.0f;

    // ---- CFO rotation via angle-addition recurrence (phase = ang*(base-2+j)) ----
    float wr[8], wi[8];
#pragma unroll
    for (int j = 0; j < 8; ++j) {
        wr[j] = ur[j] * c - ui[j] * s;
        wi[j] = ur[j] * s + ui[j] * c;
        float cn = c * cA - s * sA;
        float sn = s * cA + c * sA;
        c = cn; s = sn;
    }

    // ---- 5-tap complex conv (cross-correlation) + AWGN ----
    const float nr_[4] = {nr4.x, nr4.y, nr4.z, nr4.w};
    const float ni_[4] = {ni4.x, ni4.y, ni4.z, ni4.w};

    f32x4 yr4, yi4;
#pragma unroll
    for (int j = 0; j < 4; ++j) {
        float ar = 0.0f, ai = 0.0f;
#pragma unroll
        for (int k = 0; k < KTAPS; ++k) {
            ar = fmaf(tr[k], wr[j + k], ar);
            ar = fmaf(-ti[k], wi[j + k], ar);
            ai = fmaf(ti[k], wr[j + k], ai);
            ai = fmaf(tr[k], wi[j + k], ai);
        }
        yr4[j] = fmaf(nr_[j], scale, ar);
        yi4[j] = fmaf(ni_[j], scale, ai);
    }

    // ---- nontemporal stores: output is write-once, keep L2/L3 for inputs ----
    __builtin_nontemporal_store(yr4, reinterpret_cast<f32x4*>(out + rowoff + base));
    __builtin_nontemporal_store(yi4, reinterpret_cast<f32x4*>(out + (size_t)BB * NN + rowoff + base));
}

extern "C" void kernel_launch(void* const* d_in, const int* in_sizes, int n_in,
                              void* d_out, int out_size, void* d_ws, size_t ws_size,
                              hipStream_t stream) {
    const float* x_real     = (const float*)d_in[0];
    const float* x_imag     = (const float*)d_in[1];
    const float* ebno_db    = (const float*)d_in[2];
    const float* cfo_u      = (const float*)d_in[3];
    const float* taps_real  = (const float*)d_in[4];
    const float* taps_imag  = (const float*)d_in[5];
    const float* noise_real = (const float*)d_in[6];
    const float* noise_imag = (const float*)d_in[7];

    dim3 grid(NN / TILE, BB);
    wc_kernel<<<grid, NTHREADS, 0, stream>>>(
        x_real, x_imag, ebno_db, cfo_u, taps_real, taps_imag,
        noise_real, noise_imag, (float*)d_out);
}